// Round 11
// baseline (471.117 us; speedup 1.0000x reference)
//
#include <hip/hip_runtime.h>

typedef _Float16 f16;
typedef _Float16 f16x8 __attribute__((ext_vector_type(8)));
typedef _Float16 f16x4 __attribute__((ext_vector_type(4)));
typedef float f32x4 __attribute__((ext_vector_type(4)));

#define NCAM 6
#define CINF 512
#define MIDC 256
#define DB   112
#define HH   32
#define WW   88
#define PH   34
#define PW   90
#define NPOS (HH*WW)       /* 2816 */
#define PTILE 64
#define PT_PER_CAM 44      /* 2816/64 */

// ---- workspace layout (bytes) ----
#define O_GATE   0L
#define O_WFRED  6144L
#define O_WFBB   2365440L
#define O_WFDP   9443328L
#define O_XP0    9508864L
#define O_X1     28309504L
#define O_DP     28309504L    /* overlays X1; written only after X1's last read */
#define O_X2     37709824L
#define O_X3     47110144L
/* end: 56510464 (< 71.6MB known-good ws) */

__device__ __forceinline__ void gl_lds16(const void* g, void* l) {
  __builtin_amdgcn_global_load_lds((const __attribute__((address_space(1))) void*)g,
                                   (__attribute__((address_space(3))) void*)l, 16, 0, 0);
}

// ---------------- wfrag: weights -> MFMA A-fragment order (r9-measured version) ----------------
// Linear coalesced dst writes; src read is tap-major strided but weights (<=26MB) are
// L2-resident so the amplification never reaches HBM (r10 FETCH evidence). The r10
// LDS-pair-transpose variant regressed prep (65-73us, 1.04M bank conflicts) -> reverted.
// dst idx = (((g*TAPS+tap)*KST+ks)<<11) + (mi<<9) + (lane<<3) + j
// co = g*64+mi*16+(lane&15), ci = ks*32+(lane>>4)*8+j, src OIHW[co][ci][tap]
__device__ void wfrag_body(const float* __restrict__ src, const float* __restrict__ scale,
                           f16* __restrict__ dst, int TAPS, int CI, int CO_SRC,
                           long per, long total, int lbid, int nb) {
  long i = (long)lbid * 256 + threadIdx.x;
  long stride = (long)nb * 256;
  int KST = CI >> 5;
  for (; i < total; i += stride) {
    int conv = (int)(i / per);
    long rem = i - (long)conv * per;
    int j = (int)(rem & 7);
    int lane = (int)((rem >> 3) & 63);
    int mi = (int)((rem >> 9) & 3);
    long b = rem >> 11;
    int ks = (int)(b % KST);
    long b2 = b / KST;
    int tap = (int)(b2 % TAPS);
    int g = (int)(b2 / TAPS);
    int co = g * 64 + mi * 16 + (lane & 15);
    int ci = ks * 32 + (lane >> 4) * 8 + j;
    float v = 0.f;
    if (co < CO_SRC) {
      v = src[(long)conv * CO_SRC * CI * TAPS + ((long)co * CI + ci) * TAPS + tap];
      if (scale) v *= scale[conv * CO_SRC + co];
    }
    dst[i] = (f16)v;
  }
}

// ---------------- fused preprocessing: halo + img transpose + SE gate + wfrag x3 ----
// All sub-kernels mutually independent (disjoint outputs). Block ranges:
//   [0,915)            halo_zero
//   [915,10131)        img_trans   (9216 virtual blocks, 48x32x6)
//   [10131,10137)      se_gate     (6 blocks)
//   [10137,12185)      wfrag red   (2048-block grid-stride)
//   [12185,16281)      wfrag bb    (4096-block grid-stride)
//   [16281,16409)      wfrag dp    (128-block grid-stride)
__global__ void prep_kernel(f16* __restrict__ xp0, f16* __restrict__ X1,
                            f16* __restrict__ X2, f16* __restrict__ X3,
                            const float* __restrict__ img,
                            const float* __restrict__ intr,
                            const float* __restrict__ w1, const float* __restrict__ b1,
                            const float* __restrict__ w2, const float* __restrict__ b2,
                            const float* __restrict__ rw, const float* __restrict__ rb,
                            const float* __restrict__ ew, const float* __restrict__ eb,
                            float* __restrict__ gate,
                            const float* __restrict__ red_w, const float* __restrict__ red_s,
                            f16* __restrict__ wfred,
                            const float* __restrict__ bb_w, const float* __restrict__ bb_s,
                            f16* __restrict__ wfbb,
                            const float* __restrict__ dp_w, f16* __restrict__ wfdp) {
  __shared__ float shbuf[1056];
  const int bid = blockIdx.x;
  if (bid < 915) {
    // ---- halo zero ----
    int idx = bid * 256 + threadIdx.x;
    f16* base; int C, rem;
    if (idx < 93696) { base = xp0; C = 512; rem = idx; }
    else {
      int k = idx - 93696;
      int bsel = k / 46848;
      if (bsel >= 3) return;
      rem = k - bsel * 46848; C = 256;
      base = (bsel == 0) ? X1 : (bsel == 1) ? X2 : X3;
    }
    int chunks = C >> 3;
    int cell = rem / chunks, cc = rem - cell * chunks;
    int cam = cell / 244, p = cell - cam * 244;
    int hh, ww;
    if (p < 90)       { hh = 0;  ww = p; }
    else if (p < 180) { hh = 33; ww = p - 90; }
    else { int q = p - 180; hh = 1 + (q >> 1); ww = (q & 1) * 89; }
    long o = ((long)(cam * PH + hh) * PW + ww) * C + cc * 8;
    f16x8 z = {0,0,0,0,0,0,0,0};
    *(f16x8*)(base + o) = z;
  } else if (bid < 10131) {
    // ---- img NCHW f32 -> padded NHWC f16 ----
    int lb = bid - 915;
    int x = lb % 48;
    int h = (lb / 48) % 32;
    int n = lb / 1536;
    int wt = x % 3, ct = x / 3;
    float (*tile)[33] = (float(*)[33])shbuf;
    int tx = threadIdx.x & 31, ty = threadIdx.x >> 5;
    int w0 = wt * 32, c0 = ct * 32;
    #pragma unroll
    for (int i = 0; i < 4; ++i) {
      int cl = ty + i * 8;
      int w = w0 + tx;
      float v = 0.f;
      if (w < WW) v = img[((long)(n * CINF + c0 + cl) * HH + h) * WW + w];
      tile[cl][tx] = v;
    }
    __syncthreads();
    #pragma unroll
    for (int i = 0; i < 4; ++i) {
      int wl = ty + i * 8;
      int w = w0 + wl;
      if (w < WW)
        xp0[((long)((n * PH + h + 1) * PW + (w + 1))) * CINF + c0 + tx] = (f16)tile[tx][wl];
    }
  } else if (bid < 10137) {
    // ---- SE gate ----
    int n = bid - 10131, c = threadIdx.x;
    float* sps = shbuf;
    float* h1 = shbuf + 32;
    float* h2 = shbuf + 288;
    float* tt = shbuf + 544;
    if (c == 0) {
      float a[4][8];
      for (int i = 0; i < 4; ++i)
        for (int j = 0; j < 4; ++j) {
          a[i][j] = intr[n * 16 + i * 4 + j];
          a[i][4 + j] = (i == j) ? 1.f : 0.f;
        }
      for (int col = 0; col < 4; ++col) {
        int piv = col;
        for (int r2 = col + 1; r2 < 4; ++r2)
          if (fabsf(a[r2][col]) > fabsf(a[piv][col])) piv = r2;
        if (piv != col)
          for (int j = 0; j < 8; ++j) { float tv = a[col][j]; a[col][j] = a[piv][j]; a[piv][j] = tv; }
        float invp = 1.f / a[col][col];
        for (int j = 0; j < 8; ++j) a[col][j] *= invp;
        for (int r2 = 0; r2 < 4; ++r2)
          if (r2 != col) {
            float f = a[r2][col];
            for (int j = 0; j < 8; ++j) a[r2][j] -= f * a[col][j];
          }
      }
      float i00 = a[0][4], i11 = a[1][5];
      sps[0] = sqrtf(i00 * i00 + i11 * i11) * 1000.f;
    }
    __syncthreads();
    float sp = sps[0];
    h1[c] = fmaxf(sp * w1[c] + b1[c], 0.f);
    __syncthreads();
    float acc = b2[c];
    for (int j = 0; j < MIDC; ++j) acc += h1[j] * w2[j * MIDC + c];
    h2[c] = acc;
    __syncthreads();
    acc = rb[c];
    for (int j = 0; j < MIDC; ++j) acc += rw[c * MIDC + j] * h2[j];
    tt[c] = fmaxf(acc, 0.f);
    __syncthreads();
    acc = eb[c];
    for (int j = 0; j < MIDC; ++j) acc += ew[c * MIDC + j] * tt[j];
    gate[n * MIDC + c] = 1.f / (1.f + expf(-acc));
  } else if (bid < 12185) {
    long per = 4L * 9 * 16 * 2048;
    wfrag_body(red_w, red_s, wfred, 9, 512, 256, per, per, bid - 10137, 2048);
  } else if (bid < 16281) {
    long per = 4L * 9 * 8 * 2048;
    wfrag_body(bb_w, bb_s, wfbb, 9, 256, 256, per, 6 * per, bid - 12185, 4096);
  } else {
    long per = 2L * 1 * 8 * 2048;
    wfrag_body(dp_w, nullptr, wfdp, 1, 256, 112, per, per, bid - 16281, 128);
  }
}

// ---------------- MFMA implicit-GEMM conv (r4 champion structure) ----------------
// 128co x 64pos block, 4 waves (2x2), wave 64x32; A+B via global_load_lds into
// 2 x 24KB dbuf; __syncthreads loop (measured == counted-vmcnt, r6); co-interleaved
// bid mapping + XCD swizzle (19MB FETCH floor). Structural floor ~62us/conv0 at
// MfmaUtil ~26%: per-FLOP LDS traffic is geometry-forced (prop. 1/co+1/pos; 2x2 wave
// split provably optimal), TLP grid-capped at 2 blocks/CU by the 256-co output width;
// r0-r7 measured occupancy/fetch/pipeline/tile-geometry knobs all null or negative.
// MODE 3 fuses the depth softmax into the epilogue (dp written normalized, no logits
// round-trip). MODE 0: relu(acc+b)*gate  1: relu(acc+b)  2: relu(acc+b+res)  3: softmax->f32
template<int MODE, int CIN_T, int TAPS>
__global__ __launch_bounds__(256, 2)
void conv_mfma(const f16* __restrict__ X, const f16* __restrict__ Wf,
               const float* __restrict__ bias, const float* __restrict__ gate,
               const f16* __restrict__ res, f16* __restrict__ Yf16,
               float* __restrict__ Yf32, int co_tiles) {
  constexpr int KST = CIN_T / 32;
  constexpr int CPT = CIN_T / 64;
  constexpr int NCH = TAPS * CPT;
  constexpr int LCPT = (CPT == 8) ? 3 : 2;
  constexpr long GSTR = (long)TAPS * KST * 4096;   // bytes per weight group
  __shared__ __align__(16) char S[49152];          // 2 x (16KB A + 8KB B)

  const int t = threadIdx.x;
  const int wv = t >> 6, ln = t & 63, lm = ln & 15, quad = ln >> 4;
  const int wm = wv >> 1, wn = wv & 1;
  // XCD-aware swizzle: bid0%8 is the XCD; give each XCD a contiguous bid range.
  const int bid0 = blockIdx.x;
  const int cpx = gridDim.x >> 3;                  // grids are %8 == 0
  const int bid = (bid0 & 7) * cpx + (bid0 >> 3);
  const int co_tile = bid % co_tiles;
  const int ptile = bid / co_tiles;
  const int cam = ptile / PT_PER_CAM;
  const int pbase = (ptile % PT_PER_CAM) * PTILE;

  // B DMA setup: 2 instrs/wave, each covers 8 rows x 8 phys chunks
  const f16* gB[2]; int ldsoffB[2];
  const int clog = (ln & 7) ^ (ln >> 3);
  #pragma unroll
  for (int j = 0; j < 2; ++j) {
    int reg = j * 4 + wv;
    int r = reg * 8 + (ln >> 3);
    int pos = pbase + r;
    int hh = pos / WW, w2 = pos - hh * WW;
    gB[j] = X + ((long)((cam * PH + hh + 1) * PW + (w2 + 1))) * CIN_T + clog * 8;
    ldsoffB[j] = 16384 + reg * 1024;
  }

  // lane-constant bf addressing (bytes, within B region)
  const int base_l = (wn * 32 + lm) * 128;
  const int sx0 = ((0 * 4 + quad) ^ (lm & 7)) * 16;
  const int sx1 = ((1 * 4 + quad) ^ (lm & 7)) * 16;

  f32x4 acc[4][2];
  #pragma unroll
  for (int mi = 0; mi < 4; ++mi)
    #pragma unroll
    for (int ni = 0; ni < 2; ++ni)
      #pragma unroll
      for (int r = 0; r < 4; ++r) acc[mi][ni][r] = 0.f;

  auto choff = [&](int c) -> long {
    long off = 0;
    if (TAPS == 9) {
      int tp = c >> LCPT;
      int dy = tp / 3 - 1, dx = tp % 3 - 1;
      off = (long)(dy * PW + dx) * CIN_T;
    }
    return off + (long)(c & (CPT - 1)) * 64;
  };
  // stage one chunk's A (16KB: group0 8KB then group1 8KB) into buffer bsel
  auto stageA = [&](int bsel, int c) {
    const char* sb = (const char*)Wf + (long)c * 8192 + (long)ln * 16;
    char* db = S + bsel * 24576;
    #pragma unroll
    for (int j = 0; j < 4; ++j) {
      int seg = j * 4 + wv;                       // 0..15 (1KB segments)
      long gb = (long)(co_tile * 2 + (seg >> 3)) * GSTR;
      gl_lds16(sb + gb + (seg & 7) * 1024, db + seg * 1024);
    }
  };
  auto stageB = [&](int bsel, long curf) {
    #pragma unroll
    for (int j = 0; j < 2; ++j)
      gl_lds16(gB[j] + curf, S + bsel * 24576 + ldsoffB[j]);
  };
  auto compute = [&](int bsel) {
    const char* ab = S + bsel * 24576 + wm * 8192 + ln * 16;
    const char* bb = S + bsel * 24576 + 16384 + base_l;
    #pragma unroll
    for (int s = 0; s < 2; ++s) {
      f16x8 af[4];
      #pragma unroll
      for (int mi = 0; mi < 4; ++mi)
        af[mi] = *(const f16x8*)(ab + s * 4096 + mi * 1024);
      f16x8 bf[2];
      int sx = s ? sx1 : sx0;
      #pragma unroll
      for (int ni = 0; ni < 2; ++ni)
        bf[ni] = *(const f16x8*)(bb + ni * 2048 + sx);
      #pragma unroll
      for (int mi = 0; mi < 4; ++mi)
        #pragma unroll
        for (int ni = 0; ni < 2; ++ni)
          acc[mi][ni] = __builtin_amdgcn_mfma_f32_16x16x32_f16(af[mi], bf[ni], acc[mi][ni], 0, 0, 0);
    }
  };

  stageA(0, 0);
  stageB(0, choff(0));
  __syncthreads();

  #pragma unroll 1
  for (int c = 0; c < NCH; ++c) {
    int cur = c & 1;
    if (c + 1 < NCH) { stageA(cur ^ 1, c + 1); stageB(cur ^ 1, choff(c + 1)); }
    compute(cur);
    __syncthreads();
  }

  // ---- epilogue ----
  float4 b4[4], g4[4];
  bool skip[4];
  #pragma unroll
  for (int mi = 0; mi < 4; ++mi) {
    int co_l = wm * 64 + mi * 16 + quad * 4;
    int co_g = co_tile * 128 + co_l;
    skip[mi] = (MODE == 3) && (co_l >= DB);
    if (!skip[mi]) b4[mi] = *(const float4*)(bias + co_g);
    if (MODE == 0) g4[mi] = *(const float4*)(gate + cam * MIDC + co_g);
  }

  if (MODE == 3) {
    // fused depth softmax: stage logits to LDS [64 pos][116 bins], reduce 4 thr/pos.
    // (K-loop's final __syncthreads fences all LDS reads; S is reusable here.)
    float* P = (float*)S;
    #pragma unroll
    for (int ni = 0; ni < 2; ++ni) {
      int prow = wn * 32 + ni * 16 + lm;
      #pragma unroll
      for (int mi = 0; mi < 4; ++mi) {
        if (skip[mi]) continue;
        int co_l = wm * 64 + mi * 16 + quad * 4;
        float4 o;
        o.x = acc[mi][ni][0] + ((float*)&b4[mi])[0];
        o.y = acc[mi][ni][1] + ((float*)&b4[mi])[1];
        o.z = acc[mi][ni][2] + ((float*)&b4[mi])[2];
        o.w = acc[mi][ni][3] + ((float*)&b4[mi])[3];
        *(float4*)(P + prow * 116 + co_l) = o;
      }
    }
    __syncthreads();
    int p = t >> 2, k = t & 3;
    const float* Pr = P + p * 116;
    float m = -1e30f;
    for (int b = k; b < DB; b += 4) m = fmaxf(m, Pr[b]);
    m = fmaxf(m, __shfl_xor(m, 1));
    m = fmaxf(m, __shfl_xor(m, 2));
    float e[28];
    float ssum = 0.f;
    int cnt = 0;
    for (int b = k; b < DB; b += 4) { float ev = __expf(Pr[b] - m); e[cnt++] = ev; ssum += ev; }
    ssum += __shfl_xor(ssum, 1);
    ssum += __shfl_xor(ssum, 2);
    float inv = 1.f / ssum;
    float* op = Yf32 + ((long)(cam * NPOS + pbase + p)) * DB;
    cnt = 0;
    for (int b = k; b < DB; b += 4) op[b] = e[cnt++] * inv;
    return;
  }

  #pragma unroll
  for (int ni = 0; ni < 2; ++ni) {
    int pos = pbase + wn * 32 + ni * 16 + lm;
    int hh = pos / WW, w2 = pos - hh * WW;
    long ob = ((long)((cam * PH + hh + 1) * PW + (w2 + 1))) * MIDC + co_tile * 128;
    #pragma unroll
    for (int mi = 0; mi < 4; ++mi) {
      int co_l = wm * 64 + mi * 16 + quad * 4;
      float v[4];
      #pragma unroll
      for (int r = 0; r < 4; ++r) {
        float y = acc[mi][ni][r];
        y += ((float*)&b4[mi])[r];
        if (MODE == 0) y = fmaxf(y, 0.f) * ((float*)&g4[mi])[r];
        else if (MODE == 1) y = fmaxf(y, 0.f);
        v[r] = y;
      }
      if (MODE == 2) {
        f16x4 rv = *(const f16x4*)(res + ob + co_l);
        f16x4 o;
        #pragma unroll
        for (int r = 0; r < 4; ++r) o[r] = (f16)fmaxf(v[r] + (float)rv[r], 0.f);
        *(f16x4*)(Yf16 + ob + co_l) = o;
      } else {
        f16x4 o;
        #pragma unroll
        for (int r = 0; r < 4; ++r) o[r] = (f16)v[r];
        *(f16x4*)(Yf16 + ob + co_l) = o;
      }
    }
  }
}

// ---------------- trilinear grid sample + camera sum + normalize ----------------
// Clamped indices are ALWAYS in-bounds -> load unconditionally, mask only the WEIGHT
// (w=0 when tap invalid). Removes divergent guards around the 8 gathers so all loads
// issue under full exec mask and pipeline against L2 latency (dp 12.6MB -> L2-resident).
__global__ void sample_kernel(const float* __restrict__ grid, const float* __restrict__ dp,
                              float* __restrict__ out) {
  int v = blockIdx.x * blockDim.x + threadIdx.x;
  if (v >= 128 * 128 * 16) return;
  int vz = v & 15, vy = (v >> 4) & 127, vx = v >> 11;
  float agg = 0.f, msk = 0.f;
  #pragma unroll 2
  for (int n = 0; n < NCAM; ++n) {
    long gb = ((long)((n * 128 + vx) * 128 + vy) * 16 + vz) * 3;
    float gx = grid[gb], gy = grid[gb + 1], gz = grid[gb + 2];
    float ix = ((gx + 1.f) * (float)WW - 1.f) * 0.5f;
    float iy = ((gy + 1.f) * (float)HH - 1.f) * 0.5f;
    float iz = ((gz + 1.f) * (float)DB - 1.f) * 0.5f;
    float xf = floorf(ix), yf = floorf(iy), zf = floorf(iz);
    float fx = ix - xf, fy = iy - yf, fz = iz - zf;
    int x0 = (int)xf, y0 = (int)yf, z0 = (int)zf;
    const float* dpn = dp + (long)n * HH * WW * DB;
    float wx[2] = {1.f - fx, fx};
    float wy[2] = {1.f - fy, fy};
    float wz[2] = {1.f - fz, fz};
    int xc[2], yc[2], zc[2];
    bool xv[2], yv[2], zv[2];
    #pragma unroll
    for (int d = 0; d < 2; ++d) {
      int x = x0 + d; xv[d] = (x >= 0) && (x < WW); xc[d] = x < 0 ? 0 : (x > WW - 1 ? WW - 1 : x);
      int y = y0 + d; yv[d] = (y >= 0) && (y < HH); yc[d] = y < 0 ? 0 : (y > HH - 1 ? HH - 1 : y);
      int z = z0 + d; zv[d] = (z >= 0) && (z < DB); zc[d] = z < 0 ? 0 : (z > DB - 1 ? DB - 1 : z);
    }
    #pragma unroll
    for (int dy2 = 0; dy2 < 2; ++dy2) {
      #pragma unroll
      for (int dx2 = 0; dx2 < 2; ++dx2) {
        const float* base = dpn + ((long)(yc[dy2] * WW + xc[dx2])) * DB;
        float d0 = base[zc[0]];
        float d1 = base[zc[1]];
        float wxy = wx[dx2] * wy[dy2];
        bool vv = xv[dx2] && yv[dy2];
        float w0 = (vv && zv[0]) ? wxy * wz[0] : 0.f;
        float w1 = (vv && zv[1]) ? wxy * wz[1] : 0.f;
        msk += w0 + w1;
        agg += w0 * d0 + w1 * d1;
      }
    }
  }
  out[v] = (msk > 0.f) ? (agg / msk) : agg;
}

extern "C" void kernel_launch(void* const* d_in, const int* in_sizes, int n_in,
                              void* d_out, int out_size, void* d_ws, size_t ws_size,
                              hipStream_t stream) {
  const float* img   = (const float*)d_in[0];
  const float* intr  = (const float*)d_in[1];
  const float* grid  = (const float*)d_in[2];
  const float* red_w = (const float*)d_in[3];
  const float* red_s = (const float*)d_in[4];
  const float* red_b = (const float*)d_in[5];
  const float* w1    = (const float*)d_in[6];
  const float* b1    = (const float*)d_in[7];
  const float* w2    = (const float*)d_in[8];
  const float* b2    = (const float*)d_in[9];
  const float* rw    = (const float*)d_in[10];
  const float* rb    = (const float*)d_in[11];
  const float* ew    = (const float*)d_in[12];
  const float* eb    = (const float*)d_in[13];
  const float* bb_w  = (const float*)d_in[14];
  const float* bb_s  = (const float*)d_in[15];
  const float* bb_b  = (const float*)d_in[16];
  const float* dp_w  = (const float*)d_in[17];
  const float* dp_b  = (const float*)d_in[18];
  float* out = (float*)d_out;

  char* ws = (char*)d_ws;
  float* gate = (float*)(ws + O_GATE);
  f16* wfred  = (f16*)(ws + O_WFRED);
  f16* wfbb   = (f16*)(ws + O_WFBB);
  f16* wfdp   = (f16*)(ws + O_WFDP);
  f16* xp0    = (f16*)(ws + O_XP0);
  f16* X1     = (f16*)(ws + O_X1);
  f16* X2     = (f16*)(ws + O_X2);
  f16* X3     = (f16*)(ws + O_X3);
  float* dpb  = (float*)(ws + O_DP);

  prep_kernel<<<16409, 256, 0, stream>>>(xp0, X1, X2, X3, img,
                                         intr, w1, b1, w2, b2, rw, rb, ew, eb, gate,
                                         red_w, red_s, wfred, bb_w, bb_s, wfbb, dp_w, wfdp);

  const long WCH = 4L * 9 * 8 * 2048;  // per-conv fragment-weight stride (f16)

  conv_mfma<0, 512, 9><<<528, 256, 0, stream>>>(xp0, wfred, red_b, gate, nullptr, X1, nullptr, 2);

  conv_mfma<1, 256, 9><<<528, 256, 0, stream>>>(X1, wfbb + 0 * WCH, bb_b + 0 * 256, nullptr, nullptr, X2, nullptr, 2);
  conv_mfma<2, 256, 9><<<528, 256, 0, stream>>>(X2, wfbb + 1 * WCH, bb_b + 1 * 256, nullptr, X1, X3, nullptr, 2);
  conv_mfma<1, 256, 9><<<528, 256, 0, stream>>>(X3, wfbb + 2 * WCH, bb_b + 2 * 256, nullptr, nullptr, X2, nullptr, 2);
  conv_mfma<2, 256, 9><<<528, 256, 0, stream>>>(X2, wfbb + 3 * WCH, bb_b + 3 * 256, nullptr, X3, X1, nullptr, 2);
  conv_mfma<1, 256, 9><<<528, 256, 0, stream>>>(X1, wfbb + 4 * WCH, bb_b + 4 * 256, nullptr, nullptr, X2, nullptr, 2);
  conv_mfma<2, 256, 9><<<528, 256, 0, stream>>>(X2, wfbb + 5 * WCH, bb_b + 5 * 256, nullptr, X1, X3, nullptr, 2);

  // dp conv with fused softmax -> writes normalized dp directly
  conv_mfma<3, 256, 1><<<264, 256, 0, stream>>>(X3, wfdp, dp_b, nullptr, nullptr, nullptr, dpb, 1);

  sample_kernel<<<1024, 256, 0, stream>>>(grid, dpb, out);
}